// Round 1
// baseline (200.389 us; speedup 1.0000x reference)
//
#include <hip/hip_runtime.h>

#define BB 4
#define NN 40960
#define KK 16
#define DOUT 16
#define BN_EPS 1e-5f

typedef float f32x4 __attribute__((ext_vector_type(4)));

// One thread per (b, n, k-quad). kq in the low 2 bits of tid => for each output
// channel o, consecutive lanes write consecutive float4s: 1 KiB contiguous per
// wave store, fully coalesced.
//
// v2 changes vs 196.5us baseline:
//  - W/BN folded per-channel ONCE per block into LDS (512 B):
//      y*sc+sh = relu( sh + (w0*sc)*d + u.c + v.a ),  u=(w123+w456)*sc, v=(w789-w123)*sc
//    removes 160 W-loads + 16 rsqrtf per thread, 7->4 FMA per (o,k).
//  - nontemporal output stores: keep xyz (gather working set) resident in L2
//    instead of having 167.8 MB of streaming writes evict it.
//  - unroll-4 o-loop: bounded register pressure, params stay in LDS.
__global__ __launch_bounds__(256) void Block_72464688218281_kernel(
    const float* __restrict__ xyz,      // [B, N, 3]
    const int*   __restrict__ nidx,     // [B, N, K] (int32)
    const float* __restrict__ W,        // [DOUT, 10]
    const float* __restrict__ gamma,    // [DOUT]
    const float* __restrict__ beta,     // [DOUT]
    const float* __restrict__ rmean,    // [DOUT]
    const float* __restrict__ rvar,     // [DOUT]
    float* __restrict__ out)            // [B, DOUT, N, K]
{
    // Folded per-channel params:
    //   Pc[o] = { w0*sc, ux, uy, uz }   (dist coeff + center-point coeffs)
    //   Pn[o] = { vx, vy, vz, sh }      (neighbor-point coeffs + shift)
    __shared__ f32x4 Pc[DOUT];
    __shared__ f32x4 Pn[DOUT];
    if (threadIdx.x < DOUT) {
        const int o = threadIdx.x;
        const float istd = rsqrtf(rvar[o] + BN_EPS);
        const float sc   = gamma[o] * istd;
        const float sh   = beta[o] - gamma[o] * rmean[o] * istd;
        const float w0 = W[o * 10 + 0], w1 = W[o * 10 + 1], w2 = W[o * 10 + 2];
        const float w3 = W[o * 10 + 3], w4 = W[o * 10 + 4], w5 = W[o * 10 + 5];
        const float w6 = W[o * 10 + 6], w7 = W[o * 10 + 7], w8 = W[o * 10 + 8];
        const float w9 = W[o * 10 + 9];
        f32x4 pc; pc.x = w0 * sc;        pc.y = (w1 + w4) * sc;
                  pc.z = (w2 + w5) * sc; pc.w = (w3 + w6) * sc;
        f32x4 pn; pn.x = (w7 - w1) * sc; pn.y = (w8 - w2) * sc;
                  pn.z = (w9 - w3) * sc; pn.w = sh;
        Pc[o] = pc;
        Pn[o] = pn;
    }
    __syncthreads();

    const int t = blockIdx.x * blockDim.x + threadIdx.x;
    if (t >= BB * NN * (KK / 4)) return;

    const int kq = t & 3;          // which quad of K
    const int bn = t >> 2;         // b*N + n
    const int b  = bn / NN;
    const int n  = bn - b * NN;

    // 4 neighbor indices, 16B-aligned vector load (issued first: longest chain)
    const int4 i4 = *(const int4*)(nidx + (size_t)bn * KK + kq * 4);

    // center point
    const float* cp = xyz + (size_t)bn * 3;
    const float cx = cp[0], cy = cp[1], cz = cp[2];

    const float* xb = xyz + (size_t)b * NN * 3;
    int ids[4] = { i4.x, i4.y, i4.z, i4.w };

    float ax[4], ay[4], az[4], dd[4];
#pragma unroll
    for (int j = 0; j < 4; ++j) {
        const float* p = xb + (size_t)ids[j] * 3;
        const float nx = p[0], ny = p[1], nz = p[2];
        ax[j] = nx; ay[j] = ny; az[j] = nz;
        const float dx = cx - nx, dy = cy - ny, dz = cz - nz;
        dd[j] = sqrtf(dx * dx + dy * dy + dz * dz);
    }

    float* ob = out + (size_t)b * DOUT * NN * KK + (size_t)n * KK + kq * 4;

#pragma unroll 4
    for (int o = 0; o < DOUT; ++o) {
        const f32x4 pc = Pc[o];    // broadcast ds_read_b128 (uniform addr)
        const f32x4 pn = Pn[o];
        const float base = pn.w + pc.y * cx + pc.z * cy + pc.w * cz;

        f32x4 r;
        r.x = fmaxf(base + pc.x * dd[0] + pn.x * ax[0] + pn.y * ay[0] + pn.z * az[0], 0.0f);
        r.y = fmaxf(base + pc.x * dd[1] + pn.x * ax[1] + pn.y * ay[1] + pn.z * az[1], 0.0f);
        r.z = fmaxf(base + pc.x * dd[2] + pn.x * ax[2] + pn.y * ay[2] + pn.z * az[2], 0.0f);
        r.w = fmaxf(base + pc.x * dd[3] + pn.x * ax[3] + pn.y * ay[3] + pn.z * az[3], 0.0f);

        __builtin_nontemporal_store(r, (f32x4*)(ob + (size_t)o * NN * KK));
    }
}

extern "C" void kernel_launch(void* const* d_in, const int* in_sizes, int n_in,
                              void* d_out, int out_size, void* d_ws, size_t ws_size,
                              hipStream_t stream) {
    const float* xyz   = (const float*)d_in[0];
    // d_in[1] = feature, unused by the reference
    const int*   nidx  = (const int*)d_in[2];
    const float* W     = (const float*)d_in[3];
    const float* gamma = (const float*)d_in[4];
    const float* beta  = (const float*)d_in[5];
    const float* rmean = (const float*)d_in[6];
    const float* rvar  = (const float*)d_in[7];
    float* out = (float*)d_out;

    const int total  = BB * NN * (KK / 4);           // 655,360 threads
    const int block  = 256;
    const int grid   = (total + block - 1) / block;  // 2560 blocks (exact)
    Block_72464688218281_kernel<<<grid, block, 0, stream>>>(
        xyz, nidx, W, gamma, beta, rmean, rvar, out);
}

// Round 2
// 197.290 us; speedup vs baseline: 1.0157x; 1.0157x over previous
//
#include <hip/hip_runtime.h>

#define BB 4
#define NN 40960
#define KK 16
#define DOUT 16
#define BN_EPS 1e-5f

typedef float f32x4 __attribute__((ext_vector_type(4)));

// v3: LDS-transpose plane-major writer.
//
// Problem with v1/v2 (both ~196-200us): every wave wrote 16 x 1KiB bursts
// strided 2.62MB apart (one per (b,o) output plane). ~600 concurrent strided
// write streams per CU -> HBM page thrash -> ~1.9 TB/s effective write BW
// (fill kernel on same buffer: 6.4 TB/s). v2 proved compute/instruction count
// is irrelevant (40% VALU cut -> no change).
//
// v3: block computes 64 n x 16 k as before (thread = (n, k-quad)), but stages
// results for 8 channels at a time in 32 KiB LDS, then drains plane-major:
// each wave streams 2 planes x 4KiB of purely sequential addresses.
//  - per-CU concurrent write streams: ~16x fewer
//  - burst length per plane: 4x longer, block-coherent in time
//  - LDS 32 KiB -> 5 blocks/CU -> 20 waves/CU (enough TLP for L2 gathers)
__global__ __launch_bounds__(256) void Block_72464688218281_kernel(
    const float* __restrict__ xyz,      // [B, N, 3]
    const int*   __restrict__ nidx,     // [B, N, K] (int32)
    const float* __restrict__ W,        // [DOUT, 10]
    const float* __restrict__ gamma,    // [DOUT]
    const float* __restrict__ beta,     // [DOUT]
    const float* __restrict__ rmean,    // [DOUT]
    const float* __restrict__ rvar,     // [DOUT]
    float* __restrict__ out)            // [B, DOUT, N, K]
{
    __shared__ f32x4 stage[8][256];     // 32 KiB: 8 planes x (64 n x 4 kq)

    const int tid = threadIdx.x;
    const int t   = blockIdx.x * 256 + tid;

    const int kq = t & 3;               // which quad of K
    const int bn = t >> 2;              // b*N + n
    const int b  = bn / NN;             // uniform per block (64 | N)
    const int n0 = (blockIdx.x * 64) % NN;  // block's first n (uniform)

    // neighbor indices first (longest dependent chain)
    const int4 i4 = *(const int4*)(nidx + (size_t)bn * KK + kq * 4);

    // center point
    const float* cp = xyz + (size_t)bn * 3;
    const float cx = cp[0], cy = cp[1], cz = cp[2];

    const float* xb = xyz + (size_t)b * NN * 3;
    const int ids[4] = { i4.x, i4.y, i4.z, i4.w };

    float ax[4], ay[4], az[4], dd[4];
#pragma unroll
    for (int j = 0; j < 4; ++j) {
        const float* p = xb + (size_t)ids[j] * 3;
        const float nx = p[0], ny = p[1], nz = p[2];
        ax[j] = nx; ay[j] = ny; az[j] = nz;
        const float dx = cx - nx, dy = cy - ny, dz = cz - nz;
        dd[j] = sqrtf(dx * dx + dy * dy + dz * dz);
    }

    const int wid  = tid >> 6;          // wave id 0..3
    const int lane = tid & 63;

#pragma unroll
    for (int h = 0; h < 2; ++h) {       // two halves of 8 output channels
        // ---- compute 8 channels into LDS ----
#pragma unroll
        for (int oo = 0; oo < 8; ++oo) {
            const int o = h * 8 + oo;
            // folded conv+BN params (uniform scalar loads -> SGPRs; cheap)
            const float istd = rsqrtf(rvar[o] + BN_EPS);
            const float sc   = gamma[o] * istd;
            const float sh   = beta[o] - gamma[o] * rmean[o] * istd;
            const float pcx = W[o*10+0] * sc;
            const float ux  = (W[o*10+1] + W[o*10+4]) * sc;
            const float uy  = (W[o*10+2] + W[o*10+5]) * sc;
            const float uz  = (W[o*10+3] + W[o*10+6]) * sc;
            const float vx  = (W[o*10+7] - W[o*10+1]) * sc;
            const float vy  = (W[o*10+8] - W[o*10+2]) * sc;
            const float vz  = (W[o*10+9] - W[o*10+3]) * sc;
            const float base = sh + ux * cx + uy * cy + uz * cz;

            f32x4 r;
            r.x = fmaxf(base + pcx * dd[0] + vx * ax[0] + vy * ay[0] + vz * az[0], 0.0f);
            r.y = fmaxf(base + pcx * dd[1] + vx * ax[1] + vy * ay[1] + vz * az[1], 0.0f);
            r.z = fmaxf(base + pcx * dd[2] + vx * ax[2] + vy * ay[2] + vz * az[2], 0.0f);
            r.w = fmaxf(base + pcx * dd[3] + vx * ax[3] + vy * ay[3] + vz * az[3], 0.0f);
            stage[oo][tid] = r;         // ds_write_b128, contiguous per wave
        }
        __syncthreads();

        // ---- drain plane-major: wave wid streams planes h*8+wid*2+{0,1} ----
#pragma unroll
        for (int q = 0; q < 2; ++q) {
            const int oo = wid * 2 + q;
            const int o  = h * 8 + oo;
            float* pb = out + ((size_t)(b * DOUT + o) * NN + n0) * KK;
#pragma unroll
            for (int c = 0; c < 4; ++c) {
                const f32x4 v = stage[oo][c * 64 + lane];  // 1KiB contiguous read
                *(f32x4*)(pb + (size_t)(c * 64 + lane) * 4) = v;  // 1KiB contiguous store
            }
        }
        __syncthreads();
    }
}

extern "C" void kernel_launch(void* const* d_in, const int* in_sizes, int n_in,
                              void* d_out, int out_size, void* d_ws, size_t ws_size,
                              hipStream_t stream) {
    const float* xyz   = (const float*)d_in[0];
    // d_in[1] = feature, unused by the reference
    const int*   nidx  = (const int*)d_in[2];
    const float* W     = (const float*)d_in[3];
    const float* gamma = (const float*)d_in[4];
    const float* beta  = (const float*)d_in[5];
    const float* rmean = (const float*)d_in[6];
    const float* rvar  = (const float*)d_in[7];
    float* out = (float*)d_out;

    const int total = BB * NN * (KK / 4);      // 655,360 threads
    const int block = 256;
    const int grid  = total / block;           // 2560 blocks, exact
    Block_72464688218281_kernel<<<grid, block, 0, stream>>>(
        xyz, nidx, W, gamma, beta, rmean, rvar, out);
}